// Round 1
// baseline (368.594 us; speedup 1.0000x reference)
//
#include <hip/hip_runtime.h>

typedef __attribute__((ext_vector_type(8))) short short8;
typedef __attribute__((ext_vector_type(4))) float f32x4;

#define DEV __device__ __forceinline__

// ---------- helpers ----------
DEV unsigned short f2bf(float f) {
    unsigned int u = __float_as_uint(f);
    u += 0x7FFFu + ((u >> 16) & 1u);   // round-to-nearest-even
    return (unsigned short)(u >> 16);
}
DEV float bf2f(unsigned short h) { return __uint_as_float(((unsigned int)h) << 16); }

DEV void gload16(const void* g, void* l) {
    __builtin_amdgcn_global_load_lds(
        (const __attribute__((address_space(1))) void*)(unsigned long long)g,
        (__attribute__((address_space(3))) void*)(unsigned int)(unsigned long long)l,
        16, 0, 0);
}

// ---------- cast f32 -> bf16, 8 elems/thread ----------
__global__ void cast_bf16_kernel(const float* __restrict__ in, unsigned short* __restrict__ out, int n8) {
    int gid = blockIdx.x * 256 + threadIdx.x;
    if (gid >= n8) return;
    const f32x4* p = (const f32x4*)in + (size_t)gid * 2;
    f32x4 a = p[0], b = p[1];
    short8 v;
    v[0] = (short)f2bf(a[0]); v[1] = (short)f2bf(a[1]); v[2] = (short)f2bf(a[2]); v[3] = (short)f2bf(a[3]);
    v[4] = (short)f2bf(b[0]); v[5] = (short)f2bf(b[1]); v[6] = (short)f2bf(b[2]); v[7] = (short)f2bf(b[3]);
    *(short8*)(out + (size_t)gid * 8) = v;
}

// ---------- RoPE tables: cos/sin (256 x 32) ----------
__global__ void rope_table_kernel(float* __restrict__ cosT, float* __restrict__ sinT) {
    int gid = blockIdx.x * 256 + threadIdx.x;
    if (gid >= 256 * 32) return;
    int s = gid >> 5, i = gid & 31;
    float inv = powf(10000.0f, -(float)i * (1.0f / 32.0f));
    float f = (float)s * inv;
    cosT[gid] = cosf(f);
    sinT[gid] = sinf(f);
}

// ---------- GEMM: C = A(bf16, MxK) * W^T(bf16, NxK rows), m97 structure ----------
// MODE 0: N=3072 (Wq|Wk|Wv), epilogue scatters q,k:(B,H,S,64)  vt:(B,H,64,S)  (bf16)
// MODE 1: N=1024 (Wo), epilogue writes f32 row-major (16384x1024)
template <int MODE>
__global__ __launch_bounds__(256) void gemm128_kernel(
    const unsigned short* __restrict__ A,
    const unsigned short* __restrict__ W0,
    const unsigned short* __restrict__ W1,
    const unsigned short* __restrict__ W2,
    unsigned short* __restrict__ q,
    unsigned short* __restrict__ k,
    unsigned short* __restrict__ vt,
    float* __restrict__ outF,
    int K)
{
    __shared__ __align__(16) unsigned short As[128 * 32];
    __shared__ __align__(16) unsigned short Bs[128 * 32];
    const int tid = threadIdx.x;
    const int l = tid & 63;
    const int w = tid >> 6;
    const int wr = w >> 1, wc = w & 1;
    const int l15 = l & 15, lg = l >> 4;
    const int m0 = blockIdx.y * 128;
    const int n0 = blockIdx.x * 128;

    const unsigned short* Bp;
    int nb;
    int sel = 0;
    if (MODE == 0) {
        sel = n0 >> 10;
        Bp = (sel == 0) ? W0 : ((sel == 1) ? W1 : W2);
        nb = n0 & 1023;
    } else {
        Bp = W0;
        nb = n0;
    }

    f32x4 acc[4][4];
#pragma unroll
    for (int m = 0; m < 4; ++m)
#pragma unroll
        for (int n = 0; n < 4; ++n)
#pragma unroll
            for (int e = 0; e < 4; ++e) acc[m][n][e] = 0.f;

    for (int kt = 0; kt < K; kt += 32) {
#pragma unroll
        for (int i = 0; i < 2; ++i) {
            int off = (i * 256 + tid) * 16;  // byte offset in 8KB tile
            int row = off >> 6;              // 64B per row (32 bf16)
            int cb = off & 63;
            gload16((const char*)(A + (size_t)(m0 + row) * K + kt) + cb, (char*)As + off);
            gload16((const char*)(Bp + (size_t)(nb + row) * K + kt) + cb, (char*)Bs + off);
        }
        __syncthreads();
        short8 af[4], bfm[4];
#pragma unroll
        for (int m = 0; m < 4; ++m) af[m] = *(const short8*)(As + (wr * 64 + m * 16 + l15) * 32 + lg * 8);
#pragma unroll
        for (int n = 0; n < 4; ++n) bfm[n] = *(const short8*)(Bs + (wc * 64 + n * 16 + l15) * 32 + lg * 8);
#pragma unroll
        for (int m = 0; m < 4; ++m)
#pragma unroll
            for (int n = 0; n < 4; ++n)
                acc[m][n] = __builtin_amdgcn_mfma_f32_16x16x32_bf16(af[m], bfm[n], acc[m][n], 0, 0, 0);
        __syncthreads();
    }

    if (MODE == 0) {
#pragma unroll
        for (int m = 0; m < 4; ++m) {
#pragma unroll
            for (int n = 0; n < 4; ++n) {
#pragma unroll
                for (int i = 0; i < 4; ++i) {
                    int row = m0 + wr * 64 + m * 16 + lg * 4 + i;  // global M row
                    int col = n0 + wc * 64 + n * 16 + l15;         // 0..3071
                    int b = row >> 8, s = row & 255;
                    int c = col & 1023;
                    int h = c >> 6, d = c & 63;
                    unsigned short v = f2bf(acc[m][n][i]);
                    if (sel == 0)
                        q[((size_t)(b * 16 + h) * 256 + s) * 64 + d] = v;
                    else if (sel == 1)
                        k[((size_t)(b * 16 + h) * 256 + s) * 64 + d] = v;
                    else
                        vt[((size_t)(b * 16 + h) * 64 + d) * 256 + s] = v;
                }
            }
        }
    } else {
#pragma unroll
        for (int m = 0; m < 4; ++m) {
#pragma unroll
            for (int n = 0; n < 4; ++n) {
#pragma unroll
                for (int i = 0; i < 4; ++i) {
                    int row = m0 + wr * 64 + m * 16 + lg * 4 + i;
                    int col = n0 + wc * 64 + n * 16 + l15;
                    outF[(size_t)row * 1024 + col] = acc[m][n][i];
                }
            }
        }
    }
}

// ---------- RoPE in place on q,k (B,H,S,64), pair (i, i+32) ----------
__global__ void rope_kernel(unsigned short* __restrict__ q, unsigned short* __restrict__ k,
                            const float* __restrict__ cosT, const float* __restrict__ sinT) {
    int gid = blockIdx.x * 256 + threadIdx.x;  // over B*H*S*32 = 8388608
    int i = gid & 31;
    int r = gid >> 5;       // (b*16+h)*256 + s
    int s = r & 255;
    float c = cosT[s * 32 + i], sn = sinT[s * 32 + i];
    size_t base = (size_t)r * 64;
    float qlo = bf2f(q[base + i]), qhi = bf2f(q[base + i + 32]);
    q[base + i] = f2bf(qlo * c - qhi * sn);
    q[base + i + 32] = f2bf(qhi * c + qlo * sn);
    float klo = bf2f(k[base + i]), khi = bf2f(k[base + i + 32]);
    k[base + i] = f2bf(klo * c - khi * sn);
    k[base + i + 32] = f2bf(khi * c + klo * sn);
}

// ---------- fused attention per (b,h): 8 waves x 32 q-rows, online softmax ----------
__global__ __launch_bounds__(512) void attn_kernel(
    const unsigned short* __restrict__ qp,   // (B,H,S,64) bf16, RoPE'd
    const unsigned short* __restrict__ kp,   // (B,H,S,64) bf16, RoPE'd
    const unsigned short* __restrict__ vtp,  // (B,H,64,S) bf16
    const int* __restrict__ mask,            // (B,S)
    unsigned short* __restrict__ ao)         // (B,S,1024) bf16
{
    __shared__ __align__(16) unsigned short Ks[128 * 64];    // [key-half 0..127][d 0..63], swizzled 128B rows
    __shared__ __align__(16) unsigned short Vts[64 * 128];   // [d 0..63][key-half 0..127], swizzled 256B rows
    __shared__ __align__(16) unsigned short Ps[8][32 * 64];  // per-wave P, swizzled 128B rows

    const int bh = blockIdx.x;
    const int b = bh >> 4, h = bh & 15;
    const int tid = threadIdx.x;
    const int l = tid & 63, w = tid >> 6;
    const int l15 = l & 15, lg = l >> 4;

    const unsigned short* kbase = kp + (size_t)bh * (256 * 64);
    const unsigned short* vtbase = vtp + (size_t)bh * (64 * 256);
    const unsigned short* qbase = qp + (size_t)bh * (256 * 64) + (size_t)(w * 32) * 64;

    // Q fragments in registers (A-operand: row = l&15, k = lg*8+j)
    short8 aq[2][2];
#pragma unroll
    for (int m = 0; m < 2; ++m)
#pragma unroll
        for (int ks = 0; ks < 2; ++ks)
            aq[m][ks] = *(const short8*)(qbase + (m * 16 + l15) * 64 + ks * 32 + lg * 8);

    float m_run[2][4], l_run[2][4];
    f32x4 o[2][4];
#pragma unroll
    for (int m = 0; m < 2; ++m)
#pragma unroll
        for (int i = 0; i < 4; ++i) { m_run[m][i] = -3.0e38f; l_run[m][i] = 0.f; }
#pragma unroll
    for (int m = 0; m < 2; ++m)
#pragma unroll
        for (int n = 0; n < 4; ++n)
#pragma unroll
            for (int e = 0; e < 4; ++e) o[m][n][e] = 0.f;

    const int* mrow = mask + b * 256;

    for (int half = 0; half < 2; ++half) {
        __syncthreads();  // prior tiles' LDS reads done before restage
        // stage K half: 128 keys x 64 d = 16KB, swizzle byte^=((row&7)<<4) within 128B rows
        for (int c2 = tid; c2 < 1024; c2 += 512) {
            int off = c2 * 16;
            int row = off >> 7, cb = off & 127;
            short8 v = *(const short8*)((const char*)kbase + (size_t)half * 16384 + off);
            *(short8*)((char*)Ks + row * 128 + (cb ^ ((row & 7) << 4))) = v;
        }
        // stage Vt half: 64 d-rows x 128 keys; global row stride 512B, take [half*256, +256)
        for (int c2 = tid; c2 < 1024; c2 += 512) {
            int off = c2 * 16;
            int row = off >> 8, cb = off & 255;
            short8 v = *(const short8*)((const char*)vtbase + (size_t)row * 512 + half * 256 + cb);
            *(short8*)((char*)Vts + row * 256 + (cb ^ ((row & 7) << 4))) = v;
        }
        __syncthreads();

        for (int t2 = 0; t2 < 2; ++t2) {
            const int keyl = t2 * 64;
            const int keyg = half * 128 + keyl;

            // QK^T -> 32x64 scores per wave
            f32x4 sf[2][4];
#pragma unroll
            for (int m = 0; m < 2; ++m)
#pragma unroll
                for (int n = 0; n < 4; ++n)
#pragma unroll
                    for (int e = 0; e < 4; ++e) sf[m][n][e] = 0.f;
#pragma unroll
            for (int ks = 0; ks < 2; ++ks) {
                short8 bk[4];
#pragma unroll
                for (int n = 0; n < 4; ++n) {
                    int row = keyl + n * 16 + l15;
                    int cb = (ks * 64 + lg * 16) ^ ((row & 7) << 4);
                    bk[n] = *(const short8*)((char*)Ks + row * 128 + cb);
                }
#pragma unroll
                for (int m = 0; m < 2; ++m)
#pragma unroll
                    for (int n = 0; n < 4; ++n)
                        sf[m][n] = __builtin_amdgcn_mfma_f32_16x16x32_bf16(aq[m][ks], bk[n], sf[m][n], 0, 0, 0);
            }
            // scale + mask
            float madd[4];
#pragma unroll
            for (int n = 0; n < 4; ++n) madd[n] = mrow[keyg + n * 16 + l15] ? 0.f : -1e30f;
#pragma unroll
            for (int m = 0; m < 2; ++m)
#pragma unroll
                for (int n = 0; n < 4; ++n)
#pragma unroll
                    for (int i = 0; i < 4; ++i) sf[m][n][i] = sf[m][n][i] * 0.125f + madd[n];
            // online softmax: rows live in 16-lane groups (shfl_xor 1,2,4,8)
            float al[2][4];
#pragma unroll
            for (int m = 0; m < 2; ++m)
#pragma unroll
                for (int i = 0; i < 4; ++i) {
                    float mx = fmaxf(fmaxf(sf[m][0][i], sf[m][1][i]), fmaxf(sf[m][2][i], sf[m][3][i]));
                    mx = fmaxf(mx, __shfl_xor(mx, 1));
                    mx = fmaxf(mx, __shfl_xor(mx, 2));
                    mx = fmaxf(mx, __shfl_xor(mx, 4));
                    mx = fmaxf(mx, __shfl_xor(mx, 8));
                    float mnew = fmaxf(m_run[m][i], mx);
                    al[m][i] = __expf(m_run[m][i] - mnew);
                    m_run[m][i] = mnew;
                }
            float rs[2][4];
#pragma unroll
            for (int m = 0; m < 2; ++m)
#pragma unroll
                for (int i = 0; i < 4; ++i) rs[m][i] = 0.f;
#pragma unroll
            for (int m = 0; m < 2; ++m)
#pragma unroll
                for (int n = 0; n < 4; ++n)
#pragma unroll
                    for (int i = 0; i < 4; ++i) {
                        float p = __expf(sf[m][n][i] - m_run[m][i]);
                        sf[m][n][i] = p;
                        rs[m][i] += p;
                    }
#pragma unroll
            for (int m = 0; m < 2; ++m)
#pragma unroll
                for (int i = 0; i < 4; ++i) {
                    float r2 = rs[m][i];
                    r2 += __shfl_xor(r2, 1);
                    r2 += __shfl_xor(r2, 2);
                    r2 += __shfl_xor(r2, 4);
                    r2 += __shfl_xor(r2, 8);
                    l_run[m][i] = l_run[m][i] * al[m][i] + r2;
                }
#pragma unroll
            for (int m = 0; m < 2; ++m)
#pragma unroll
                for (int n = 0; n < 4; ++n)
#pragma unroll
                    for (int i = 0; i < 4; ++i) o[m][n][i] *= al[m][i];

            // P (D-layout) -> LDS bf16 (swizzled), then read back as A-operand
            __syncthreads();
#pragma unroll
            for (int m = 0; m < 2; ++m)
#pragma unroll
                for (int n = 0; n < 4; ++n)
#pragma unroll
                    for (int i = 0; i < 4; ++i) {
                        int row = m * 16 + lg * 4 + i;
                        int cb = ((n * 16 + l15) * 2) ^ ((row & 7) << 4);
                        *(unsigned short*)((char*)Ps[w] + row * 128 + cb) = f2bf(sf[m][n][i]);
                    }
            __syncthreads();
            // PV
#pragma unroll
            for (int ks = 0; ks < 2; ++ks) {
                short8 pa[2];
#pragma unroll
                for (int m = 0; m < 2; ++m) {
                    int row = m * 16 + l15;
                    int cb = (ks * 64 + lg * 16) ^ ((row & 7) << 4);
                    pa[m] = *(const short8*)((char*)Ps[w] + row * 128 + cb);
                }
                short8 vb[4];
#pragma unroll
                for (int n = 0; n < 4; ++n) {
                    int row = n * 16 + l15;  // d
                    int cb = (keyl * 2 + ks * 64 + lg * 16) ^ ((row & 7) << 4);
                    vb[n] = *(const short8*)((char*)Vts + row * 256 + cb);
                }
#pragma unroll
                for (int m = 0; m < 2; ++m)
#pragma unroll
                    for (int n = 0; n < 4; ++n)
                        o[m][n] = __builtin_amdgcn_mfma_f32_16x16x32_bf16(pa[m], vb[n], o[m][n], 0, 0, 0);
            }
        }
    }

    // epilogue: (B,S,1024) bf16
    unsigned short* aop = ao + ((size_t)(b * 256 + w * 32)) * 1024 + h * 64;
#pragma unroll
    for (int m = 0; m < 2; ++m)
#pragma unroll
        for (int n = 0; n < 4; ++n)
#pragma unroll
            for (int i = 0; i < 4; ++i) {
                int row = m * 16 + lg * 4 + i;
                int d = n * 16 + l15;
                aop[(size_t)row * 1024 + d] = f2bf(o[m][n][i] / l_run[m][i]);
            }
}

// ---------- launch ----------
extern "C" void kernel_launch(void* const* d_in, const int* in_sizes, int n_in,
                              void* d_out, int out_size, void* d_ws, size_t ws_size,
                              hipStream_t stream) {
    const float* x = (const float*)d_in[0];
    const int* mask = (const int*)d_in[1];
    const float* Wq = (const float*)d_in[2];
    const float* Wk = (const float*)d_in[3];
    const float* Wv = (const float*)d_in[4];
    const float* Wo = (const float*)d_in[5];
    float* out = (float*)d_out;

    char* ws = (char*)d_ws;
    size_t off = 0;
    auto alloc = [&](size_t bytes) -> char* {
        char* p = ws + off;
        off = (off + bytes + 255) & ~(size_t)255;
        return p;
    };
    // total ~143 MB
    unsigned short* xb = (unsigned short*)alloc((size_t)16384 * 1024 * 2);  // bf16 x; later aliased as attn_out
    unsigned short* wqb = (unsigned short*)alloc((size_t)1024 * 1024 * 2);
    unsigned short* wkb = (unsigned short*)alloc((size_t)1024 * 1024 * 2);
    unsigned short* wvb = (unsigned short*)alloc((size_t)1024 * 1024 * 2);
    unsigned short* wob = (unsigned short*)alloc((size_t)1024 * 1024 * 2);
    unsigned short* q = (unsigned short*)alloc((size_t)16384 * 1024 * 2);   // (B,H,S,64)
    unsigned short* k = (unsigned short*)alloc((size_t)16384 * 1024 * 2);   // (B,H,S,64)
    unsigned short* vt = (unsigned short*)alloc((size_t)16384 * 1024 * 2);  // (B,H,64,S)
    float* cosT = (float*)alloc(256 * 32 * 4);
    float* sinT = (float*)alloc(256 * 32 * 4);

    cast_bf16_kernel<<<16777216 / 8 / 256, 256, 0, stream>>>(x, xb, 16777216 / 8);
    cast_bf16_kernel<<<1048576 / 8 / 256, 256, 0, stream>>>(Wq, wqb, 1048576 / 8);
    cast_bf16_kernel<<<1048576 / 8 / 256, 256, 0, stream>>>(Wk, wkb, 1048576 / 8);
    cast_bf16_kernel<<<1048576 / 8 / 256, 256, 0, stream>>>(Wv, wvb, 1048576 / 8);
    cast_bf16_kernel<<<1048576 / 8 / 256, 256, 0, stream>>>(Wo, wob, 1048576 / 8);
    rope_table_kernel<<<32, 256, 0, stream>>>(cosT, sinT);

    gemm128_kernel<0><<<dim3(24, 128), 256, 0, stream>>>(xb, wqb, wkb, wvb, q, k, vt, nullptr, 1024);
    rope_kernel<<<32768, 256, 0, stream>>>(q, k, cosT, sinT);
    attn_kernel<<<1024, 512, 0, stream>>>(q, k, vt, mask, xb /* attn_out, aliases xb */);
    gemm128_kernel<1><<<dim3(8, 128), 256, 0, stream>>>(xb, wob, nullptr, nullptr, nullptr, nullptr, nullptr, out, 1024);

    (void)in_sizes; (void)n_in; (void)out_size; (void)ws_size;
}

// Round 2
// 308.461 us; speedup vs baseline: 1.1949x; 1.1949x over previous
//
#include <hip/hip_runtime.h>

typedef __attribute__((ext_vector_type(8))) short short8;
typedef __attribute__((ext_vector_type(4))) float f32x4;

#define DEV __device__ __forceinline__

// ---------- helpers ----------
DEV unsigned short f2bf(float f) {
    unsigned int u = __float_as_uint(f);
    u += 0x7FFFu + ((u >> 16) & 1u);   // round-to-nearest-even
    return (unsigned short)(u >> 16);
}
DEV float bf2f(unsigned short h) { return __uint_as_float(((unsigned int)h) << 16); }

DEV void gload16(const void* g, void* l) {
    __builtin_amdgcn_global_load_lds(
        (const __attribute__((address_space(1))) void*)(unsigned long long)g,
        (__attribute__((address_space(3))) void*)(unsigned int)(unsigned long long)l,
        16, 0, 0);
}

// ---------- cast f32 -> bf16, 8 elems/thread ----------
__global__ void cast_bf16_kernel(const float* __restrict__ in, unsigned short* __restrict__ out, int n8) {
    int gid = blockIdx.x * 256 + threadIdx.x;
    if (gid >= n8) return;
    const f32x4* p = (const f32x4*)in + (size_t)gid * 2;
    f32x4 a = p[0], b = p[1];
    short8 v;
    v[0] = (short)f2bf(a[0]); v[1] = (short)f2bf(a[1]); v[2] = (short)f2bf(a[2]); v[3] = (short)f2bf(a[3]);
    v[4] = (short)f2bf(b[0]); v[5] = (short)f2bf(b[1]); v[6] = (short)f2bf(b[2]); v[7] = (short)f2bf(b[3]);
    *(short8*)(out + (size_t)gid * 8) = v;
}

// ---------- RoPE tables: cos/sin (256 x 32) ----------
__global__ void rope_table_kernel(float* __restrict__ cosT, float* __restrict__ sinT) {
    int gid = blockIdx.x * 256 + threadIdx.x;
    if (gid >= 256 * 32) return;
    int s = gid >> 5, i = gid & 31;
    float inv = powf(10000.0f, -(float)i * (1.0f / 32.0f));
    float f = (float)s * inv;
    cosT[gid] = cosf(f);
    sinT[gid] = sinf(f);
}

// =====================================================================
// 256x256 tile, BK=64 (2 K-halves of 32), 8 waves (2x4), 512 threads.
// 4 phases per K-tile, counted vmcnt(8) at phases 2 & 4, raw s_barrier,
// setprio around MFMA clusters, XOR-swizzled LDS (chunk ^= (row>>1)&3).
// MODE 0: N=3072 (Wq|Wk|Wv); epilogue applies RoPE to q,k and scatters
//         q,k:(B,H,S,64), vt:(B,H,64,S) bf16.
// MODE 1: N=1024 (Wo); epilogue writes f32 row-major (16384x1024).
// =====================================================================
#define NT 16  // K=1024 / 64

#define STAGE2(SW, SBUF, SKH, TS) do {                                         \
    int ts_ = (TS) < NT ? (TS) : (NT - 1);                                     \
    const unsigned short* sp_ = SW##base + (size_t)ts_ * 64 + (SKH) * 32;      \
    gload16(sp_ + rel0, &SW##l[SBUF][SKH][(size_t)tid * 8]);                   \
    gload16(sp_ + rel1, &SW##l[SBUF][SKH][(size_t)(tid + 512) * 8]);           \
} while (0)

#define MM(MH, MI, NI)                                                         \
    acc[(MH)*4+(MI)][(NI)] = __builtin_amdgcn_mfma_f32_16x16x32_bf16(          \
        av##MI, bva[(NI)], acc[(MH)*4+(MI)][(NI)], 0, 0, 0)

#define PH(BUF, KH, MH, SW, SBUF, SKH, TS, DW) do {                            \
    short8 av0 = *(const short8*)&Al[BUF][KH][aoff[(MH)*4 + 0]];               \
    short8 av1 = *(const short8*)&Al[BUF][KH][aoff[(MH)*4 + 1]];               \
    short8 av2 = *(const short8*)&Al[BUF][KH][aoff[(MH)*4 + 2]];               \
    short8 av3 = *(const short8*)&Al[BUF][KH][aoff[(MH)*4 + 3]];               \
    if ((MH) == 0) {                                                           \
        bva[0] = *(const short8*)&Bl[BUF][KH][boff[0]];                        \
        bva[1] = *(const short8*)&Bl[BUF][KH][boff[1]];                        \
        bva[2] = *(const short8*)&Bl[BUF][KH][boff[2]];                        \
        bva[3] = *(const short8*)&Bl[BUF][KH][boff[3]];                        \
    }                                                                          \
    STAGE2(SW, SBUF, SKH, TS);                                                 \
    if (DW) asm volatile("s_waitcnt vmcnt(8)" ::: "memory");                   \
    asm volatile("" ::: "memory");                                             \
    __builtin_amdgcn_s_barrier();                                              \
    asm volatile("" ::: "memory");                                             \
    __builtin_amdgcn_s_setprio(1);                                             \
    MM(MH,0,0); MM(MH,1,0); MM(MH,2,0); MM(MH,3,0);                            \
    MM(MH,0,1); MM(MH,1,1); MM(MH,2,1); MM(MH,3,1);                            \
    MM(MH,0,2); MM(MH,1,2); MM(MH,2,2); MM(MH,3,2);                            \
    MM(MH,0,3); MM(MH,1,3); MM(MH,2,3); MM(MH,3,3);                            \
    __builtin_amdgcn_s_setprio(0);                                             \
    asm volatile("" ::: "memory");                                             \
    __builtin_amdgcn_s_barrier();                                              \
    asm volatile("" ::: "memory");                                             \
} while (0)

#define TILE(BUF, T)                                                           \
    PH(BUF, 0, 0, A, (BUF)^1, 1, (T)+1, 0);                                    \
    PH(BUF, 0, 1, B, (BUF)^1, 1, (T)+1, 1);                                    \
    PH(BUF, 1, 0, A, (BUF),   0, (T)+2, 0);                                    \
    PH(BUF, 1, 1, B, (BUF),   0, (T)+2, 1);

template <int MODE>
__global__ __launch_bounds__(512, 2) void gemm256_kernel(
    const unsigned short* __restrict__ A,
    const unsigned short* __restrict__ W0,
    const unsigned short* __restrict__ W1,
    const unsigned short* __restrict__ W2,
    unsigned short* __restrict__ q,
    unsigned short* __restrict__ k,
    unsigned short* __restrict__ vt,
    float* __restrict__ outF,
    const float* __restrict__ cosT,
    const float* __restrict__ sinT)
{
    __shared__ __align__(16) unsigned short Al[2][2][8192];  // [buf][kh][256*32]
    __shared__ __align__(16) unsigned short Bl[2][2][8192];

    const int tid = threadIdx.x;
    const int l = tid & 63;
    const int w = tid >> 6;
    const int wr = w >> 2, wc = w & 3;
    const int l15 = l & 15, lg = l >> 4;

    // XCD-aware block swizzle (grid % 8 == 0 for both modes)
    const int nwg = gridDim.x;
    const int bid = blockIdx.x;
    const int cpx = nwg >> 3;
    const int swz = (bid & 7) * cpx + (bid >> 3);
    const int NBX = (MODE == 0) ? 12 : 4;
    const int bx = swz % NBX, by = swz / NBX;
    const int m0 = by * 256, n0 = bx * 256;

    const unsigned short* Bp;
    int nb, sel = 0;
    if (MODE == 0) {
        sel = n0 >> 10;
        Bp = (sel == 0) ? W0 : ((sel == 1) ? W1 : W2);
        nb = n0 & 1023;
    } else {
        Bp = W0;
        nb = n0;
    }

    // stage source offsets (pre-swizzled so linear LDS dest + swizzled read = identity)
    const int f0 = tid, f1 = tid + 512;
    const int rel0 = (f0 >> 2) * 1024 + (((f0 & 3) ^ ((f0 >> 3) & 3)) * 8);
    const int rel1 = (f1 >> 2) * 1024 + (((f1 & 3) ^ ((f1 >> 3) & 3)) * 8);
    const unsigned short* Abase = A + (size_t)m0 * 1024;
    const unsigned short* Bbase = Bp + (size_t)nb * 1024;

    // swizzled LDS read offsets (ushort units)
    int aoff[8], boff[4];
#pragma unroll
    for (int mi = 0; mi < 8; ++mi) {
        int row = wr * 128 + mi * 16 + l15;
        aoff[mi] = row * 32 + ((lg ^ ((row >> 1) & 3)) * 8);
    }
#pragma unroll
    for (int ni = 0; ni < 4; ++ni) {
        int row = wc * 64 + ni * 16 + l15;
        boff[ni] = row * 32 + ((lg ^ ((row >> 1) & 3)) * 8);
    }

    f32x4 acc[8][4];
#pragma unroll
    for (int mi = 0; mi < 8; ++mi)
#pragma unroll
        for (int ni = 0; ni < 4; ++ni)
#pragma unroll
            for (int e = 0; e < 4; ++e) acc[mi][ni][e] = 0.f;

    short8 bva[4];

    // prologue: Ak0(0),Bk0(0),Ak1(0),Bk1(0),Ak0(1),Bk0(1); gate k0(0)
    STAGE2(A, 0, 0, 0); STAGE2(B, 0, 0, 0);
    STAGE2(A, 0, 1, 0); STAGE2(B, 0, 1, 0);
    STAGE2(A, 1, 0, 1); STAGE2(B, 1, 0, 1);
    asm volatile("s_waitcnt vmcnt(8)" ::: "memory");
    asm volatile("" ::: "memory");
    __builtin_amdgcn_s_barrier();
    asm volatile("" ::: "memory");

#pragma unroll 1
    for (int it = 0; it < NT / 2; ++it) {
        const int t0 = it * 2;
        TILE(0, t0);
        TILE(1, t0 + 1);
    }

    // ---------------- epilogue ----------------
    if (MODE == 0) {
#pragma unroll
        for (int mi = 0; mi < 8; ++mi) {
#pragma unroll
            for (int i = 0; i < 4; ++i) {
                int grow = m0 + wr * 128 + mi * 16 + lg * 4 + i;
                int b = grow >> 8, s = grow & 255;
                if (sel < 2) {
                    // RoPE: pair (d, d+32) = (acc[..][ni], acc[..][ni+2]), d = ni*16+l15
#pragma unroll
                    for (int ni = 0; ni < 2; ++ni) {
                        int d = ni * 16 + l15;
                        float c = cosT[s * 32 + d], sn = sinT[s * 32 + d];
                        float lo = acc[mi][ni][i], hi = acc[mi][ni + 2][i];
                        acc[mi][ni][i] = lo * c - hi * sn;
                        acc[mi][ni + 2][i] = hi * c + lo * sn;
                    }
                }
#pragma unroll
                for (int ni = 0; ni < 4; ++ni) {
                    int col = n0 + wc * 64 + ni * 16 + l15;
                    int cc = col & 1023;
                    int h = cc >> 6, d = cc & 63;
                    unsigned short v = f2bf(acc[mi][ni][i]);
                    if (sel == 0)
                        q[((size_t)(b * 16 + h) * 256 + s) * 64 + d] = v;
                    else if (sel == 1)
                        k[((size_t)(b * 16 + h) * 256 + s) * 64 + d] = v;
                    else
                        vt[((size_t)(b * 16 + h) * 64 + d) * 256 + s] = v;
                }
            }
        }
    } else {
#pragma unroll
        for (int mi = 0; mi < 8; ++mi) {
#pragma unroll
            for (int i = 0; i < 4; ++i) {
                int grow = m0 + wr * 128 + mi * 16 + lg * 4 + i;
#pragma unroll
                for (int ni = 0; ni < 4; ++ni) {
                    int col = n0 + wc * 64 + ni * 16 + l15;
                    outF[(size_t)grow * 1024 + col] = acc[mi][ni][i];
                }
            }
        }
    }
}

// ---------- fused attention per (b,h): 8 waves x 32 q-rows, online softmax ----------
__global__ __launch_bounds__(512) void attn_kernel(
    const unsigned short* __restrict__ qp,   // (B,H,S,64) bf16, RoPE'd
    const unsigned short* __restrict__ kp,   // (B,H,S,64) bf16, RoPE'd
    const unsigned short* __restrict__ vtp,  // (B,H,64,S) bf16
    const int* __restrict__ mask,            // (B,S)
    unsigned short* __restrict__ ao)         // (B,S,1024) bf16
{
    __shared__ __align__(16) unsigned short Ks[128 * 64];    // [key 0..127][d 0..63], swizzled 128B rows
    __shared__ __align__(16) unsigned short Vts[64 * 128];   // [d 0..63][key 0..127], swizzled 256B rows
    __shared__ __align__(16) unsigned short Ps[8][32 * 64];  // per-wave P, swizzled 128B rows

    const int bh = blockIdx.x;
    const int b = bh >> 4, h = bh & 15;
    const int tid = threadIdx.x;
    const int l = tid & 63, w = tid >> 6;
    const int l15 = l & 15, lg = l >> 4;

    const unsigned short* kbase = kp + (size_t)bh * (256 * 64);
    const unsigned short* vtbase = vtp + (size_t)bh * (64 * 256);
    const unsigned short* qbase = qp + (size_t)bh * (256 * 64) + (size_t)(w * 32) * 64;

    short8 aq[2][2];
#pragma unroll
    for (int m = 0; m < 2; ++m)
#pragma unroll
        for (int ks = 0; ks < 2; ++ks)
            aq[m][ks] = *(const short8*)(qbase + (m * 16 + l15) * 64 + ks * 32 + lg * 8);

    float m_run[2][4], l_run[2][4];
    f32x4 o[2][4];
#pragma unroll
    for (int m = 0; m < 2; ++m)
#pragma unroll
        for (int i = 0; i < 4; ++i) { m_run[m][i] = -3.0e38f; l_run[m][i] = 0.f; }
#pragma unroll
    for (int m = 0; m < 2; ++m)
#pragma unroll
        for (int n = 0; n < 4; ++n)
#pragma unroll
            for (int e = 0; e < 4; ++e) o[m][n][e] = 0.f;

    const int* mrow = mask + b * 256;

    for (int half = 0; half < 2; ++half) {
        __syncthreads();
        for (int c2 = tid; c2 < 1024; c2 += 512) {
            int off = c2 * 16;
            int row = off >> 7, cb = off & 127;
            short8 v = *(const short8*)((const char*)kbase + (size_t)half * 16384 + off);
            *(short8*)((char*)Ks + row * 128 + (cb ^ ((row & 7) << 4))) = v;
        }
        for (int c2 = tid; c2 < 1024; c2 += 512) {
            int off = c2 * 16;
            int row = off >> 8, cb = off & 255;
            short8 v = *(const short8*)((const char*)vtbase + (size_t)row * 512 + half * 256 + cb);
            *(short8*)((char*)Vts + row * 256 + (cb ^ ((row & 7) << 4))) = v;
        }
        __syncthreads();

        for (int t2 = 0; t2 < 2; ++t2) {
            const int keyl = t2 * 64;
            const int keyg = half * 128 + keyl;

            f32x4 sf[2][4];
#pragma unroll
            for (int m = 0; m < 2; ++m)
#pragma unroll
                for (int n = 0; n < 4; ++n)
#pragma unroll
                    for (int e = 0; e < 4; ++e) sf[m][n][e] = 0.f;
#pragma unroll
            for (int ks = 0; ks < 2; ++ks) {
                short8 bk[4];
#pragma unroll
                for (int n = 0; n < 4; ++n) {
                    int row = keyl + n * 16 + l15;
                    int cb = (ks * 64 + lg * 16) ^ ((row & 7) << 4);
                    bk[n] = *(const short8*)((char*)Ks + row * 128 + cb);
                }
#pragma unroll
                for (int m = 0; m < 2; ++m)
#pragma unroll
                    for (int n = 0; n < 4; ++n)
                        sf[m][n] = __builtin_amdgcn_mfma_f32_16x16x32_bf16(aq[m][ks], bk[n], sf[m][n], 0, 0, 0);
            }
            float madd[4];
#pragma unroll
            for (int n = 0; n < 4; ++n) madd[n] = mrow[keyg + n * 16 + l15] ? 0.f : -1e30f;
#pragma unroll
            for (int m = 0; m < 2; ++m)
#pragma unroll
                for (int n = 0; n < 4; ++n)
#pragma unroll
                    for (int i = 0; i < 4; ++i) sf[m][n][i] = sf[m][n][i] * 0.125f + madd[n];
            float al[2][4];
#pragma unroll
            for (int m = 0; m < 2; ++m)
#pragma unroll
                for (int i = 0; i < 4; ++i) {
                    float mx = fmaxf(fmaxf(sf[m][0][i], sf[m][1][i]), fmaxf(sf[m][2][i], sf[m][3][i]));
                    mx = fmaxf(mx, __shfl_xor(mx, 1));
                    mx = fmaxf(mx, __shfl_xor(mx, 2));
                    mx = fmaxf(mx, __shfl_xor(mx, 4));
                    mx = fmaxf(mx, __shfl_xor(mx, 8));
                    float mnew = fmaxf(m_run[m][i], mx);
                    al[m][i] = __expf(m_run[m][i] - mnew);
                    m_run[m][i] = mnew;
                }
            float rs[2][4];
#pragma unroll
            for (int m = 0; m < 2; ++m)
#pragma unroll
                for (int i = 0; i < 4; ++i) rs[m][i] = 0.f;
#pragma unroll
            for (int m = 0; m < 2; ++m)
#pragma unroll
                for (int n = 0; n < 4; ++n)
#pragma unroll
                    for (int i = 0; i < 4; ++i) {
                        float p = __expf(sf[m][n][i] - m_run[m][i]);
                        sf[m][n][i] = p;
                        rs[m][i] += p;
                    }
#pragma unroll
            for (int m = 0; m < 2; ++m)
#pragma unroll
                for (int i = 0; i < 4; ++i) {
                    float r2 = rs[m][i];
                    r2 += __shfl_xor(r2, 1);
                    r2 += __shfl_xor(r2, 2);
                    r2 += __shfl_xor(r2, 4);
                    r2 += __shfl_xor(r2, 8);
                    l_run[m][i] = l_run[m][i] * al[m][i] + r2;
                }
#pragma unroll
            for (int m = 0; m < 2; ++m)
#pragma unroll
                for (int n = 0; n < 4; ++n)
#pragma unroll
                    for (int i = 0; i < 4; ++i) o[m][n][i] *= al[m][i];

            __syncthreads();
#pragma unroll
            for (int m = 0; m < 2; ++m)
#pragma unroll
                for (int n = 0; n < 4; ++n)
#pragma unroll
                    for (int i = 0; i < 4; ++i) {
                        int row = m * 16 + lg * 4 + i;
                        int cb = ((n * 16 + l15) * 2) ^ ((row & 7) << 4);
                        *(unsigned short*)((char*)Ps[w] + row * 128 + cb) = f2bf(sf[m][n][i]);
                    }
            __syncthreads();
#pragma unroll
            for (int ks = 0; ks < 2; ++ks) {
                short8 pa[2];
#pragma unroll
                for (int m = 0; m < 2; ++m) {
                    int row = m * 16 + l15;
                    int cb = (ks * 64 + lg * 16) ^ ((row & 7) << 4);
                    pa[m] = *(const short8*)((char*)Ps[w] + row * 128 + cb);
                }
                short8 vb[4];
#pragma unroll
                for (int n = 0; n < 4; ++n) {
                    int row = n * 16 + l15;
                    int cb = (keyl * 2 + ks * 64 + lg * 16) ^ ((row & 7) << 4);
                    vb[n] = *(const short8*)((char*)Vts + row * 256 + cb);
                }
#pragma unroll
                for (int m = 0; m < 2; ++m)
#pragma unroll
                    for (int n = 0; n < 4; ++n)
                        o[m][n] = __builtin_amdgcn_mfma_f32_16x16x32_bf16(pa[m], vb[n], o[m][n], 0, 0, 0);
            }
        }
    }

    unsigned short* aop = ao + ((size_t)(b * 256 + w * 32)) * 1024 + h * 64;
#pragma unroll
    for (int m = 0; m < 2; ++m)
#pragma unroll
        for (int n = 0; n < 4; ++n)
#pragma unroll
            for (int i = 0; i < 4; ++i) {
                int row = m * 16 + lg * 4 + i;
                int d = n * 16 + l15;
                aop[(size_t)row * 1024 + d] = f2bf(o[m][n][i] / l_run[m][i]);
            }
}

// ---------- launch ----------
extern "C" void kernel_launch(void* const* d_in, const int* in_sizes, int n_in,
                              void* d_out, int out_size, void* d_ws, size_t ws_size,
                              hipStream_t stream) {
    const float* x = (const float*)d_in[0];
    const int* mask = (const int*)d_in[1];
    const float* Wq = (const float*)d_in[2];
    const float* Wk = (const float*)d_in[3];
    const float* Wv = (const float*)d_in[4];
    const float* Wo = (const float*)d_in[5];
    float* out = (float*)d_out;

    char* ws = (char*)d_ws;
    size_t off = 0;
    auto alloc = [&](size_t bytes) -> char* {
        char* p = ws + off;
        off = (off + bytes + 255) & ~(size_t)255;
        return p;
    };
    unsigned short* xb = (unsigned short*)alloc((size_t)16384 * 1024 * 2);  // bf16 x; later aliased as attn_out
    unsigned short* wqb = (unsigned short*)alloc((size_t)1024 * 1024 * 2);
    unsigned short* wkb = (unsigned short*)alloc((size_t)1024 * 1024 * 2);
    unsigned short* wvb = (unsigned short*)alloc((size_t)1024 * 1024 * 2);
    unsigned short* wob = (unsigned short*)alloc((size_t)1024 * 1024 * 2);
    unsigned short* q = (unsigned short*)alloc((size_t)16384 * 1024 * 2);   // (B,H,S,64)
    unsigned short* k = (unsigned short*)alloc((size_t)16384 * 1024 * 2);   // (B,H,S,64)
    unsigned short* vt = (unsigned short*)alloc((size_t)16384 * 1024 * 2);  // (B,H,64,S)
    float* cosT = (float*)alloc(256 * 32 * 4);
    float* sinT = (float*)alloc(256 * 32 * 4);

    cast_bf16_kernel<<<16777216 / 8 / 256, 256, 0, stream>>>(x, xb, 16777216 / 8);
    cast_bf16_kernel<<<1048576 / 8 / 256, 256, 0, stream>>>(Wq, wqb, 1048576 / 8);
    cast_bf16_kernel<<<1048576 / 8 / 256, 256, 0, stream>>>(Wk, wkb, 1048576 / 8);
    cast_bf16_kernel<<<1048576 / 8 / 256, 256, 0, stream>>>(Wv, wvb, 1048576 / 8);
    cast_bf16_kernel<<<1048576 / 8 / 256, 256, 0, stream>>>(Wo, wob, 1048576 / 8);
    rope_table_kernel<<<32, 256, 0, stream>>>(cosT, sinT);

    gemm256_kernel<0><<<768, 512, 0, stream>>>(xb, wqb, wkb, wvb, q, k, vt, nullptr, cosT, sinT);
    attn_kernel<<<1024, 512, 0, stream>>>(q, k, vt, mask, xb /* attn_out, aliases xb */);
    gemm256_kernel<1><<<256, 512, 0, stream>>>(xb, wob, nullptr, nullptr, nullptr, nullptr, nullptr, out, nullptr, nullptr);

    (void)in_sizes; (void)n_in; (void)out_size; (void)ws_size;
}

// Round 3
// 298.720 us; speedup vs baseline: 1.2339x; 1.0326x over previous
//
#include <hip/hip_runtime.h>

typedef __attribute__((ext_vector_type(8))) short short8;
typedef __attribute__((ext_vector_type(4))) float f32x4;

#define DEV __device__ __forceinline__

// ---------- helpers ----------
DEV unsigned short f2bf(float f) {
    unsigned int u = __float_as_uint(f);
    u += 0x7FFFu + ((u >> 16) & 1u);   // round-to-nearest-even
    return (unsigned short)(u >> 16);
}
DEV float bf2f(unsigned short h) { return __uint_as_float(((unsigned int)h) << 16); }

DEV void gload16(const void* g, void* l) {
    __builtin_amdgcn_global_load_lds(
        (const __attribute__((address_space(1))) void*)(unsigned long long)g,
        (__attribute__((address_space(3))) void*)(unsigned int)(unsigned long long)l,
        16, 0, 0);
}

// ---------- cast f32 -> bf16, 8 elems/thread ----------
__global__ void cast_bf16_kernel(const float* __restrict__ in, unsigned short* __restrict__ out, int n8) {
    int gid = blockIdx.x * 256 + threadIdx.x;
    if (gid >= n8) return;
    const f32x4* p = (const f32x4*)in + (size_t)gid * 2;
    f32x4 a = p[0], b = p[1];
    short8 v;
    v[0] = (short)f2bf(a[0]); v[1] = (short)f2bf(a[1]); v[2] = (short)f2bf(a[2]); v[3] = (short)f2bf(a[3]);
    v[4] = (short)f2bf(b[0]); v[5] = (short)f2bf(b[1]); v[6] = (short)f2bf(b[2]); v[7] = (short)f2bf(b[3]);
    *(short8*)(out + (size_t)gid * 8) = v;
}

// ---------- cast 4 weights (each 1M floats) in one dispatch ----------
__global__ void cast_w4_kernel(const float* __restrict__ w0, const float* __restrict__ w1,
                               const float* __restrict__ w2, const float* __restrict__ w3,
                               unsigned short* __restrict__ o0, unsigned short* __restrict__ o1,
                               unsigned short* __restrict__ o2, unsigned short* __restrict__ o3) {
    int gid = blockIdx.x * 256 + threadIdx.x;  // 4 * 131072
    int sel = gid >> 17, idx = gid & 131071;
    const float* in = (sel == 0) ? w0 : (sel == 1) ? w1 : (sel == 2) ? w2 : w3;
    unsigned short* out = (sel == 0) ? o0 : (sel == 1) ? o1 : (sel == 2) ? o2 : o3;
    const f32x4* p = (const f32x4*)in + (size_t)idx * 2;
    f32x4 a = p[0], b = p[1];
    short8 v;
    v[0] = (short)f2bf(a[0]); v[1] = (short)f2bf(a[1]); v[2] = (short)f2bf(a[2]); v[3] = (short)f2bf(a[3]);
    v[4] = (short)f2bf(b[0]); v[5] = (short)f2bf(b[1]); v[6] = (short)f2bf(b[2]); v[7] = (short)f2bf(b[3]);
    *(short8*)(out + (size_t)idx * 8) = v;
}

// ---------- RoPE tables: cos/sin (256 x 32) ----------
__global__ void rope_table_kernel(float* __restrict__ cosT, float* __restrict__ sinT) {
    int gid = blockIdx.x * 256 + threadIdx.x;
    if (gid >= 256 * 32) return;
    int s = gid >> 5, i = gid & 31;
    float inv = powf(10000.0f, -(float)i * (1.0f / 32.0f));
    float f = (float)s * inv;
    cosT[gid] = cosf(f);
    sinT[gid] = sinf(f);
}

// =====================================================================
// 256x256 tile, BK=32, 8 waves (2x4), 512 threads, 4 LDS buffers (128KB),
// depth-3 global prefetch (stage t+3, vmcnt(4)/tile), A-frag register
// double-buffer (A(t+1) read during MFMA(t)), B-frags early in-phase,
// 1 barrier/tile, setprio around MFMA cluster, XOR-swizzled LDS.
// MODE 0: N=3072 (Wq|Wk|Wv); RoPE fused; scatters q,k:(B,H,S,64),
//         vt:(B,H,64,S) bf16.   MODE 1: N=1024 (Wo); f32 row-major out.
// =====================================================================
#define NT 32  // K=1024 / 32

#define STAGE(SB, TS) do {                                                     \
    int ts_ = (TS) < NT ? (TS) : (NT - 1);                                     \
    const unsigned short* as_ = Abase + (size_t)ts_ * 32;                      \
    const unsigned short* bs_ = Bbase + (size_t)ts_ * 32;                      \
    gload16(as_ + rel0, &Al[SB][(size_t)tid * 8]);                             \
    gload16(as_ + rel1, &Al[SB][(size_t)(tid + 512) * 8]);                     \
    gload16(bs_ + rel0, &Bl[SB][(size_t)tid * 8]);                             \
    gload16(bs_ + rel1, &Bl[SB][(size_t)(tid + 512) * 8]);                     \
} while (0)

#define RDB(BUF) do {                                                          \
    bv[0] = *(const short8*)&Bl[BUF][boff[0]];                                 \
    bv[1] = *(const short8*)&Bl[BUF][boff[1]];                                 \
    bv[2] = *(const short8*)&Bl[BUF][boff[2]];                                 \
    bv[3] = *(const short8*)&Bl[BUF][boff[3]];                                 \
} while (0)

#define RDA(FR, BUF) do {                                                      \
    FR[0] = *(const short8*)&Al[BUF][aoff[0]];                                 \
    FR[1] = *(const short8*)&Al[BUF][aoff[1]];                                 \
    FR[2] = *(const short8*)&Al[BUF][aoff[2]];                                 \
    FR[3] = *(const short8*)&Al[BUF][aoff[3]];                                 \
    FR[4] = *(const short8*)&Al[BUF][aoff[4]];                                 \
    FR[5] = *(const short8*)&Al[BUF][aoff[5]];                                 \
    FR[6] = *(const short8*)&Al[BUF][aoff[6]];                                 \
    FR[7] = *(const short8*)&Al[BUF][aoff[7]];                                 \
} while (0)

#define MFMA32(F) do {                                                         \
    _Pragma("unroll")                                                          \
    for (int ni = 0; ni < 4; ++ni)                                             \
        _Pragma("unroll")                                                      \
        for (int mi = 0; mi < 8; ++mi)                                         \
            acc[mi][ni] = __builtin_amdgcn_mfma_f32_16x16x32_bf16(             \
                F[mi], bv[ni], acc[mi][ni], 0, 0, 0);                          \
} while (0)

#define TILEB(T, CURB, NXTB, STB, FCUR, FNXT) do {                             \
    RDB(CURB);                                                                 \
    RDA(FNXT, NXTB);                                                           \
    STAGE(STB, (T) + 3);                                                       \
    __builtin_amdgcn_s_setprio(1);                                             \
    MFMA32(FCUR);                                                              \
    __builtin_amdgcn_s_setprio(0);                                             \
    asm volatile("s_waitcnt vmcnt(4)" ::: "memory");                           \
    __builtin_amdgcn_s_barrier();                                              \
    asm volatile("" ::: "memory");                                             \
} while (0)

template <int MODE>
__global__ __launch_bounds__(512, 2) void gemm256_kernel(
    const unsigned short* __restrict__ A,
    const unsigned short* __restrict__ W0,
    const unsigned short* __restrict__ W1,
    const unsigned short* __restrict__ W2,
    unsigned short* __restrict__ q,
    unsigned short* __restrict__ k,
    unsigned short* __restrict__ vt,
    float* __restrict__ outF,
    const float* __restrict__ cosT,
    const float* __restrict__ sinT)
{
    __shared__ __align__(16) unsigned short Al[4][8192];  // 4 x 16KB
    __shared__ __align__(16) unsigned short Bl[4][8192];  // 4 x 16KB

    const int tid = threadIdx.x;
    const int l = tid & 63;
    const int w = tid >> 6;
    const int wr = w >> 2, wc = w & 3;
    const int l15 = l & 15, lg = l >> 4;

    // XCD-aware block swizzle (grid % 8 == 0 for both modes)
    const int nwg = gridDim.x;
    const int bid = blockIdx.x;
    const int cpx = nwg >> 3;
    const int swz = (bid & 7) * cpx + (bid >> 3);
    const int NBX = (MODE == 0) ? 12 : 4;
    const int bx = swz % NBX, by = swz / NBX;
    const int m0 = by * 256, n0 = bx * 256;

    const unsigned short* Bp;
    int nb, sel = 0;
    if (MODE == 0) {
        sel = n0 >> 10;
        Bp = (sel == 0) ? W0 : ((sel == 1) ? W1 : W2);
        nb = n0 & 1023;
    } else {
        Bp = W0;
        nb = n0;
    }

    // stage source offsets (inverse-swizzled source; linear LDS dest)
    const int f0 = tid, f1 = tid + 512;
    const int rel0 = (f0 >> 2) * 1024 + (((f0 & 3) ^ ((f0 >> 3) & 3)) * 8);
    const int rel1 = (f1 >> 2) * 1024 + (((f1 & 3) ^ ((f1 >> 3) & 3)) * 8);
    const unsigned short* Abase = A + (size_t)m0 * 1024;
    const unsigned short* Bbase = Bp + (size_t)nb * 1024;

    // swizzled LDS read offsets (ushort units)
    int aoff[8], boff[4];
#pragma unroll
    for (int mi = 0; mi < 8; ++mi) {
        int row = wr * 128 + mi * 16 + l15;
        aoff[mi] = row * 32 + ((lg ^ ((row >> 1) & 3)) * 8);
    }
#pragma unroll
    for (int ni = 0; ni < 4; ++ni) {
        int row = wc * 64 + ni * 16 + l15;
        boff[ni] = row * 32 + ((lg ^ ((row >> 1) & 3)) * 8);
    }

    f32x4 acc[8][4];
#pragma unroll
    for (int mi = 0; mi < 8; ++mi)
#pragma unroll
        for (int ni = 0; ni < 4; ++ni)
#pragma unroll
            for (int e = 0; e < 4; ++e) acc[mi][ni][e] = 0.f;

    short8 bv[4], fA[8], fB[8];

    // prologue: stage tiles 0,1,2; ensure 0,1 done (2 in flight); read A(0)
    STAGE(0, 0);
    STAGE(1, 1);
    STAGE(2, 2);
    asm volatile("s_waitcnt vmcnt(4)" ::: "memory");
    __builtin_amdgcn_s_barrier();
    asm volatile("" ::: "memory");
    RDA(fA, 0);

#pragma unroll 1
    for (int it = 0; it < NT / 4; ++it) {
        const int t0 = it * 4;
        TILEB(t0 + 0, 0, 1, 3, fA, fB);
        TILEB(t0 + 1, 1, 2, 0, fB, fA);
        TILEB(t0 + 2, 2, 3, 1, fA, fB);
        TILEB(t0 + 3, 3, 0, 2, fB, fA);
    }

    // ---------------- epilogue ----------------
    if (MODE == 0) {
#pragma unroll
        for (int mi = 0; mi < 8; ++mi) {
#pragma unroll
            for (int i = 0; i < 4; ++i) {
                int grow = m0 + wr * 128 + mi * 16 + lg * 4 + i;
                int b = grow >> 8, s = grow & 255;
                if (sel < 2) {
                    // RoPE: pair (d, d+32) = (acc[..][ni], acc[..][ni+2]), d = ni*16+l15
#pragma unroll
                    for (int ni = 0; ni < 2; ++ni) {
                        int d = ni * 16 + l15;
                        float c = cosT[s * 32 + d], sn = sinT[s * 32 + d];
                        float lo = acc[mi][ni][i], hi = acc[mi][ni + 2][i];
                        acc[mi][ni][i] = lo * c - hi * sn;
                        acc[mi][ni + 2][i] = hi * c + lo * sn;
                    }
                }
#pragma unroll
                for (int ni = 0; ni < 4; ++ni) {
                    int col = n0 + wc * 64 + ni * 16 + l15;
                    int cc = col & 1023;
                    int h = cc >> 6, d = cc & 63;
                    unsigned short v = f2bf(acc[mi][ni][i]);
                    if (sel == 0)
                        q[((size_t)(b * 16 + h) * 256 + s) * 64 + d] = v;
                    else if (sel == 1)
                        k[((size_t)(b * 16 + h) * 256 + s) * 64 + d] = v;
                    else
                        vt[((size_t)(b * 16 + h) * 64 + d) * 256 + s] = v;
                }
            }
        }
    } else {
#pragma unroll
        for (int mi = 0; mi < 8; ++mi) {
#pragma unroll
            for (int i = 0; i < 4; ++i) {
                int grow = m0 + wr * 128 + mi * 16 + lg * 4 + i;
#pragma unroll
                for (int ni = 0; ni < 4; ++ni) {
                    int col = n0 + wc * 64 + ni * 16 + l15;
                    outF[(size_t)grow * 1024 + col] = acc[mi][ni][i];
                }
            }
        }
    }
}

// ---------- fused attention per (b,h): 8 waves x 32 q-rows, online softmax ----------
__global__ __launch_bounds__(512) void attn_kernel(
    const unsigned short* __restrict__ qp,   // (B,H,S,64) bf16, RoPE'd
    const unsigned short* __restrict__ kp,   // (B,H,S,64) bf16, RoPE'd
    const unsigned short* __restrict__ vtp,  // (B,H,64,S) bf16
    const int* __restrict__ mask,            // (B,S)
    unsigned short* __restrict__ ao)         // (B,S,1024) bf16
{
    __shared__ __align__(16) unsigned short Ks[128 * 64];    // [key 0..127][d 0..63], swizzled 128B rows
    __shared__ __align__(16) unsigned short Vts[64 * 128];   // [d 0..63][key 0..127], swizzled 256B rows
    __shared__ __align__(16) unsigned short Ps[8][32 * 64];  // per-wave P, swizzled 128B rows

    const int bh = blockIdx.x;
    const int b = bh >> 4, h = bh & 15;
    const int tid = threadIdx.x;
    const int l = tid & 63, w = tid >> 6;
    const int l15 = l & 15, lg = l >> 4;

    const unsigned short* kbase = kp + (size_t)bh * (256 * 64);
    const unsigned short* vtbase = vtp + (size_t)bh * (64 * 256);
    const unsigned short* qbase = qp + (size_t)bh * (256 * 64) + (size_t)(w * 32) * 64;

    short8 aq[2][2];
#pragma unroll
    for (int m = 0; m < 2; ++m)
#pragma unroll
        for (int ks = 0; ks < 2; ++ks)
            aq[m][ks] = *(const short8*)(qbase + (m * 16 + l15) * 64 + ks * 32 + lg * 8);

    float m_run[2][4], l_run[2][4];
    f32x4 o[2][4];
#pragma unroll
    for (int m = 0; m < 2; ++m)
#pragma unroll
        for (int i = 0; i < 4; ++i) { m_run[m][i] = -3.0e38f; l_run[m][i] = 0.f; }
#pragma unroll
    for (int m = 0; m < 2; ++m)
#pragma unroll
        for (int n = 0; n < 4; ++n)
#pragma unroll
            for (int e = 0; e < 4; ++e) o[m][n][e] = 0.f;

    const int* mrow = mask + b * 256;

    for (int half = 0; half < 2; ++half) {
        __syncthreads();
        for (int c2 = tid; c2 < 1024; c2 += 512) {
            int off = c2 * 16;
            int row = off >> 7, cb = off & 127;
            short8 v = *(const short8*)((const char*)kbase + (size_t)half * 16384 + off);
            *(short8*)((char*)Ks + row * 128 + (cb ^ ((row & 7) << 4))) = v;
        }
        for (int c2 = tid; c2 < 1024; c2 += 512) {
            int off = c2 * 16;
            int row = off >> 8, cb = off & 255;
            short8 v = *(const short8*)((const char*)vtbase + (size_t)row * 512 + half * 256 + cb);
            *(short8*)((char*)Vts + row * 256 + (cb ^ ((row & 7) << 4))) = v;
        }
        __syncthreads();

        for (int t2 = 0; t2 < 2; ++t2) {
            const int keyl = t2 * 64;
            const int keyg = half * 128 + keyl;

            f32x4 sf[2][4];
#pragma unroll
            for (int m = 0; m < 2; ++m)
#pragma unroll
                for (int n = 0; n < 4; ++n)
#pragma unroll
                    for (int e = 0; e < 4; ++e) sf[m][n][e] = 0.f;
#pragma unroll
            for (int ks = 0; ks < 2; ++ks) {
                short8 bk[4];
#pragma unroll
                for (int n = 0; n < 4; ++n) {
                    int row = keyl + n * 16 + l15;
                    int cb = (ks * 64 + lg * 16) ^ ((row & 7) << 4);
                    bk[n] = *(const short8*)((char*)Ks + row * 128 + cb);
                }
#pragma unroll
                for (int m = 0; m < 2; ++m)
#pragma unroll
                    for (int n = 0; n < 4; ++n)
                        sf[m][n] = __builtin_amdgcn_mfma_f32_16x16x32_bf16(aq[m][ks], bk[n], sf[m][n], 0, 0, 0);
            }
            float madd[4];
#pragma unroll
            for (int n = 0; n < 4; ++n) madd[n] = mrow[keyg + n * 16 + l15] ? 0.f : -1e30f;
#pragma unroll
            for (int m = 0; m < 2; ++m)
#pragma unroll
                for (int n = 0; n < 4; ++n)
#pragma unroll
                    for (int i = 0; i < 4; ++i) sf[m][n][i] = sf[m][n][i] * 0.125f + madd[n];
            float al[2][4];
#pragma unroll
            for (int m = 0; m < 2; ++m)
#pragma unroll
                for (int i = 0; i < 4; ++i) {
                    float mx = fmaxf(fmaxf(sf[m][0][i], sf[m][1][i]), fmaxf(sf[m][2][i], sf[m][3][i]));
                    mx = fmaxf(mx, __shfl_xor(mx, 1));
                    mx = fmaxf(mx, __shfl_xor(mx, 2));
                    mx = fmaxf(mx, __shfl_xor(mx, 4));
                    mx = fmaxf(mx, __shfl_xor(mx, 8));
                    float mnew = fmaxf(m_run[m][i], mx);
                    al[m][i] = __expf(m_run[m][i] - mnew);
                    m_run[m][i] = mnew;
                }
            float rs[2][4];
#pragma unroll
            for (int m = 0; m < 2; ++m)
#pragma unroll
                for (int i = 0; i < 4; ++i) rs[m][i] = 0.f;
#pragma unroll
            for (int m = 0; m < 2; ++m)
#pragma unroll
                for (int n = 0; n < 4; ++n)
#pragma unroll
                    for (int i = 0; i < 4; ++i) {
                        float p = __expf(sf[m][n][i] - m_run[m][i]);
                        sf[m][n][i] = p;
                        rs[m][i] += p;
                    }
#pragma unroll
            for (int m = 0; m < 2; ++m)
#pragma unroll
                for (int i = 0; i < 4; ++i) {
                    float r2 = rs[m][i];
                    r2 += __shfl_xor(r2, 1);
                    r2 += __shfl_xor(r2, 2);
                    r2 += __shfl_xor(r2, 4);
                    r2 += __shfl_xor(r2, 8);
                    l_run[m][i] = l_run[m][i] * al[m][i] + r2;
                }
#pragma unroll
            for (int m = 0; m < 2; ++m)
#pragma unroll
                for (int n = 0; n < 4; ++n)
#pragma unroll
                    for (int i = 0; i < 4; ++i) o[m][n][i] *= al[m][i];

            __syncthreads();
#pragma unroll
            for (int m = 0; m < 2; ++m)
#pragma unroll
                for (int n = 0; n < 4; ++n)
#pragma unroll
                    for (int i = 0; i < 4; ++i) {
                        int row = m * 16 + lg * 4 + i;
                        int cb = ((n * 16 + l15) * 2) ^ ((row & 7) << 4);
                        *(unsigned short*)((char*)Ps[w] + row * 128 + cb) = f2bf(sf[m][n][i]);
                    }
            __syncthreads();
#pragma unroll
            for (int ks = 0; ks < 2; ++ks) {
                short8 pa[2];
#pragma unroll
                for (int m = 0; m < 2; ++m) {
                    int row = m * 16 + l15;
                    int cb = (ks * 64 + lg * 16) ^ ((row & 7) << 4);
                    pa[m] = *(const short8*)((char*)Ps[w] + row * 128 + cb);
                }
                short8 vb[4];
#pragma unroll
                for (int n = 0; n < 4; ++n) {
                    int row = n * 16 + l15;
                    int cb = (keyl * 2 + ks * 64 + lg * 16) ^ ((row & 7) << 4);
                    vb[n] = *(const short8*)((char*)Vts + row * 256 + cb);
                }
#pragma unroll
                for (int m = 0; m < 2; ++m)
#pragma unroll
                    for (int n = 0; n < 4; ++n)
                        o[m][n] = __builtin_amdgcn_mfma_f32_16x16x32_bf16(pa[m], vb[n], o[m][n], 0, 0, 0);
            }
        }
    }

    unsigned short* aop = ao + ((size_t)(b * 256 + w * 32)) * 1024 + h * 64;
#pragma unroll
    for (int m = 0; m < 2; ++m)
#pragma unroll
        for (int n = 0; n < 4; ++n)
#pragma unroll
            for (int i = 0; i < 4; ++i) {
                int row = m * 16 + lg * 4 + i;
                int d = n * 16 + l15;
                aop[(size_t)row * 1024 + d] = f2bf(o[m][n][i] / l_run[m][i]);
            }
}

// ---------- launch ----------
extern "C" void kernel_launch(void* const* d_in, const int* in_sizes, int n_in,
                              void* d_out, int out_size, void* d_ws, size_t ws_size,
                              hipStream_t stream) {
    const float* x = (const float*)d_in[0];
    const int* mask = (const int*)d_in[1];
    const float* Wq = (const float*)d_in[2];
    const float* Wk = (const float*)d_in[3];
    const float* Wv = (const float*)d_in[4];
    const float* Wo = (const float*)d_in[5];
    float* out = (float*)d_out;

    char* ws = (char*)d_ws;
    size_t off = 0;
    auto alloc = [&](size_t bytes) -> char* {
        char* p = ws + off;
        off = (off + bytes + 255) & ~(size_t)255;
        return p;
    };
    unsigned short* xb = (unsigned short*)alloc((size_t)16384 * 1024 * 2);  // bf16 x; later aliased as attn_out
    unsigned short* wqb = (unsigned short*)alloc((size_t)1024 * 1024 * 2);
    unsigned short* wkb = (unsigned short*)alloc((size_t)1024 * 1024 * 2);
    unsigned short* wvb = (unsigned short*)alloc((size_t)1024 * 1024 * 2);
    unsigned short* wob = (unsigned short*)alloc((size_t)1024 * 1024 * 2);
    unsigned short* q = (unsigned short*)alloc((size_t)16384 * 1024 * 2);   // (B,H,S,64)
    unsigned short* k = (unsigned short*)alloc((size_t)16384 * 1024 * 2);   // (B,H,S,64)
    unsigned short* vt = (unsigned short*)alloc((size_t)16384 * 1024 * 2);  // (B,H,64,S)
    float* cosT = (float*)alloc(256 * 32 * 4);
    float* sinT = (float*)alloc(256 * 32 * 4);

    cast_bf16_kernel<<<16777216 / 8 / 256, 256, 0, stream>>>(x, xb, 16777216 / 8);
    cast_w4_kernel<<<4 * 131072 / 256, 256, 0, stream>>>(Wq, Wk, Wv, Wo, wqb, wkb, wvb, wob);
    rope_table_kernel<<<32, 256, 0, stream>>>(cosT, sinT);

    gemm256_kernel<0><<<768, 512, 0, stream>>>(xb, wqb, wkb, wvb, q, k, vt, nullptr, cosT, sinT);
    attn_kernel<<<1024, 512, 0, stream>>>(q, k, vt, mask, xb /* attn_out, aliases xb */);
    gemm256_kernel<1><<<256, 512, 0, stream>>>(xb, wob, nullptr, nullptr, nullptr, nullptr, nullptr, out, nullptr, nullptr);

    (void)in_sizes; (void)n_in; (void)out_size; (void)ws_size;
}